// Round 7
// baseline (1584.143 us; speedup 1.0000x reference)
//
#include <hip/hip_runtime.h>
#include <hip/hip_bf16.h>
#include <stdint.h>

#define HD 4096
#define VD 32000
#define BT 2048        // B*T rows
#define TT 512
#define IGNORE_IDX (-100)

// bf16 8-wave main GEMM geometry
#define BM 256
#define BN 256
#define BKT 64
#define KT (HD / BKT)          // 64 K-tiles
#define NB (VD / BN)           // 125
#define MB (BT / BM)           // 8
#define NWG2 (MB * NB * 2)     // 2000

// partials granularity (64 columns per chunk) — shared with f32 fallback
#define NCHUNK (VD / 64)       // 500

typedef __attribute__((ext_vector_type(8))) short short8;
typedef __attribute__((ext_vector_type(4))) float f32x4;
typedef __attribute__((ext_vector_type(16))) float f32x16;

__device__ __forceinline__ uint16_t f2bf(float f) {
    uint32_t u = __float_as_uint(f);
    u += 0x7FFFu + ((u >> 16) & 1u);   // round-to-nearest-even
    return (uint16_t)(u >> 16);
}

__device__ __forceinline__ void gload16(const void* g, void* l) {
    __builtin_amdgcn_global_load_lds(
        (const __attribute__((address_space(1))) void*)g,
        (__attribute__((address_space(3))) void*)l, 16, 0, 0);
}

#define SBAR __builtin_amdgcn_sched_barrier(0)

// ---------------- kernel 0a: convert x inputs f32 -> bf16 ----------------
__global__ void convert_x(const float* __restrict__ x0, const float* __restrict__ x1,
                          uint16_t* __restrict__ xbf) {
    const int64_t n4 = (int64_t)BT * HD / 4;
    ushort4* o0 = (ushort4*)xbf;
    ushort4* o1 = (ushort4*)(xbf + (int64_t)BT * HD);
    for (int64_t i = blockIdx.x * (int64_t)blockDim.x + threadIdx.x; i < n4;
         i += (int64_t)gridDim.x * blockDim.x) {
        float4 a = ((const float4*)x0)[i];
        float4 b = ((const float4*)x1)[i];
        ushort4 ua, ub;
        ua.x = f2bf(a.x); ua.y = f2bf(a.y); ua.z = f2bf(a.z); ua.w = f2bf(a.w);
        ub.x = f2bf(b.x); ub.y = f2bf(b.y); ub.z = f2bf(b.z); ub.w = f2bf(b.w);
        o0[i] = ua;
        o1[i] = ub;
    }
}

// ---------------- kernel 0b: convert weights f32 -> bf16 ----------------
__global__ void convert_w(const float* __restrict__ w0, const float* __restrict__ w1,
                          uint16_t* __restrict__ wbf) {
    const int64_t n4 = (int64_t)VD * HD / 4;
    ushort4* o0 = (ushort4*)wbf;
    ushort4* o1 = (ushort4*)(wbf + (int64_t)VD * HD);
    for (int64_t i = blockIdx.x * (int64_t)blockDim.x + threadIdx.x; i < n4;
         i += (int64_t)gridDim.x * blockDim.x) {
        float4 a = ((const float4*)w0)[i];
        float4 b = ((const float4*)w1)[i];
        ushort4 ua, ub;
        ua.x = f2bf(a.x); ua.y = f2bf(a.y); ua.z = f2bf(a.z); ua.w = f2bf(a.w);
        ub.x = f2bf(b.x); ub.y = f2bf(b.y); ub.z = f2bf(b.z); ub.w = f2bf(b.w);
        o0[i] = ua;
        o1[i] = ub;
    }
}

// ---------------- main GEMM tile body: 32x32x16 MFMA, 4 phases (one k-step each) ----------------
// All 8 prefetch loads for tile t+1 issue at phase 0 (NXT buffer free from tile start).
// Tile-end: vmcnt(0) (loads issued ~3 phases earlier -> cheap) + barrier = the only join.
// Per phase: 6 ds_read_b128 (4 A-frags + 2 B-frags) -> 8 independent MFMAs -> barrier.
#define MFMA32(a, b, c) __builtin_amdgcn_mfma_f32_32x32x16_bf16(a, b, c, 0, 0, 0)

template<int CUR>
__device__ __forceinline__ void tile_body(
    int t,
    const uint16_t* __restrict__ agp, const uint16_t* __restrict__ bgp,
    char* aLdst, char* bLdst,
    const char* pAk0, const char* pAk1, const char* pAk2, const char* pAk3,
    const char* pBk0, const char* pBk1, const char* pBk2, const char* pBk3,
    f32x16 (&acc)[4][2])
{
    constexpr int CB  = CUR * 32768;
    constexpr int NXB = (CUR ^ 1) * 32768;
    const bool more = (t + 1) < KT;
    const int ko = (t + 1) * BKT;

#define BARR do { SBAR; __builtin_amdgcn_s_barrier(); SBAR; } while (0)
#define PHASE(PA, PB, STG) do {                                        \
    short8 a0 = *(const short8*)(PA + 0 * 4096 + CB);                  \
    short8 a1 = *(const short8*)(PA + 1 * 4096 + CB);                  \
    short8 a2 = *(const short8*)(PA + 2 * 4096 + CB);                  \
    short8 a3 = *(const short8*)(PA + 3 * 4096 + CB);                  \
    short8 b0 = *(const short8*)(PB + 0 * 4096 + CB);                  \
    short8 b1 = *(const short8*)(PB + 1 * 4096 + CB);                  \
    STG                                                                \
    __builtin_amdgcn_s_setprio(1);                                     \
    acc[0][0] = MFMA32(a0, b0, acc[0][0]);                             \
    acc[1][0] = MFMA32(a1, b0, acc[1][0]);                             \
    acc[2][0] = MFMA32(a2, b0, acc[2][0]);                             \
    acc[3][0] = MFMA32(a3, b0, acc[3][0]);                             \
    acc[0][1] = MFMA32(a0, b1, acc[0][1]);                             \
    acc[1][1] = MFMA32(a1, b1, acc[1][1]);                             \
    acc[2][1] = MFMA32(a2, b1, acc[2][1]);                             \
    acc[3][1] = MFMA32(a3, b1, acc[3][1]);                             \
    __builtin_amdgcn_s_setprio(0);                                     \
} while (0)

    // phase 0: + stage ALL 8 chunks for tile t+1 into NXT
    PHASE(pAk0, pBk0,
        if (more) {
            gload16(bgp + (size_t)(0 * 32) * HD + ko, bLdst + NXB + 0 * 4096);
            gload16(bgp + (size_t)(1 * 32) * HD + ko, bLdst + NXB + 1 * 4096);
            gload16(bgp + (size_t)(2 * 32) * HD + ko, bLdst + NXB + 2 * 4096);
            gload16(bgp + (size_t)(3 * 32) * HD + ko, bLdst + NXB + 3 * 4096);
            gload16(agp + (size_t)(0 * 32) * HD + ko, aLdst + NXB + 0 * 4096);
            gload16(agp + (size_t)(1 * 32) * HD + ko, aLdst + NXB + 1 * 4096);
            gload16(agp + (size_t)(2 * 32) * HD + ko, aLdst + NXB + 2 * 4096);
            gload16(agp + (size_t)(3 * 32) * HD + ko, aLdst + NXB + 3 * 4096);
        });
    BARR;
    // phase 1
    PHASE(pAk1, pBk1, ;);
    BARR;
    // phase 2
    PHASE(pAk2, pBk2, ;);
    BARR;
    // phase 3 + tile-end join (vmcnt(0): my 8 loads issued at ph0 are long landed)
    PHASE(pAk3, pBk3, ;);
    SBAR; asm volatile("s_waitcnt vmcnt(0)" ::: "memory"); SBAR;
    __builtin_amdgcn_s_barrier();
    SBAR;
#undef PHASE
#undef BARR
}

// ---------------- kernel 1 (main): 256x256 32x32-MFMA GEMM + LSE partials ----------------
__global__ __launch_bounds__(512, 2) void gemm_lse_bf(
    const uint16_t* __restrict__ xbf, const uint16_t* __restrict__ wbf,
    const float* __restrict__ b0, const float* __restrict__ b1,
    const int* __restrict__ target,
    float* __restrict__ partials, float* __restrict__ tgtlog)
{
    __shared__ uint16_t As[2 * BM * BKT];  // 64 KB (2 buffers)
    __shared__ uint16_t Bs[2 * BN * BKT];  // 64 KB

    const int orig = blockIdx.x;
    const int wgid = (orig & 7) * (NWG2 / 8) + (orig >> 3);
    const int mb    = wgid & 7;
    const int rest  = wgid >> 3;
    const int nb    = rest % NB;
    const int model = rest / NB;

    const uint16_t* xb = xbf + (size_t)model * BT * HD;
    const uint16_t* wb = wbf + (size_t)model * VD * HD;
    const float* bias  = model ? b1 : b0;

    const int row0 = mb * BM;
    const int c0   = nb * BN;

    const int tid    = threadIdx.x;
    const int lane   = tid & 63;
    const int wid    = tid >> 6;       // 0..7
    const int wr     = wid >> 2;       // 0..1  (M half)
    const int wc     = wid & 3;        // 0..3  (N quarter)

    const int l31 = lane & 31;
    const int hi  = lane >> 5;

    // staging (unchanged from R4/R5, verified): wave-local quadrants, LDS dest
    // linear 1KB chunks, global source slot pre-swizzled by (row&7).
    const int srow8 = lane >> 3;               // 0..7
    const int slot  = (lane & 7) ^ srow8;      // pre-swizzled source slot
    const uint16_t* agp = xb + (size_t)(row0 + wr * 128 + wc * 8 + srow8) * HD + slot * 8;
    const int bq = wr * 2 + (wc & 1);          // 0..3: stager index within B-half
    const uint16_t* bgp = wb + (size_t)(c0 + (wc >> 1) * 128 + bq * 8 + srow8) * HD + slot * 8;
    char* aLdst = (char*)As + wr * 16384 + wc * 1024;          // + j*4096 + buf*32768
    char* bLdst = (char*)Bs + (wc >> 1) * 16384 + bq * 1024;   // + j*4096 + buf*32768

    // 32x32 fragment read pointers. Lane holds row (l31 within 32-row block),
    // k = ks*16 + hi*8 .. +7 -> byte slot = ks*2+hi, swizzled by XOR (row&7).
    // Per-rf/cf: +4096 immediate; per-buffer: +32768 immediate.
    const int row_a = wr * 128 + l31;
    const int row_b = wc * 64 + l31;
    const int r7a = row_a & 7;
    const int r7b = row_b & 7;
    const char* pAk0 = (const char*)As + row_a * 128 + (((0 * 2 + hi) ^ r7a) << 4);
    const char* pAk1 = (const char*)As + row_a * 128 + (((1 * 2 + hi) ^ r7a) << 4);
    const char* pAk2 = (const char*)As + row_a * 128 + (((2 * 2 + hi) ^ r7a) << 4);
    const char* pAk3 = (const char*)As + row_a * 128 + (((3 * 2 + hi) ^ r7a) << 4);
    const char* pBk0 = (const char*)Bs + row_b * 128 + (((0 * 2 + hi) ^ r7b) << 4);
    const char* pBk1 = (const char*)Bs + row_b * 128 + (((1 * 2 + hi) ^ r7b) << 4);
    const char* pBk2 = (const char*)Bs + row_b * 128 + (((2 * 2 + hi) ^ r7b) << 4);
    const char* pBk3 = (const char*)Bs + row_b * 128 + (((3 * 2 + hi) ^ r7b) << 4);

    f32x16 acc[4][2];
#pragma unroll
    for (int i = 0; i < 4; ++i)
#pragma unroll
        for (int j = 0; j < 2; ++j)
#pragma unroll
            for (int e = 0; e < 16; ++e) acc[i][j][e] = 0.f;

    // prologue: stage tile 0 into buf 0, drain, barrier
#pragma unroll
    for (int j = 0; j < 4; ++j)
        gload16(bgp + (size_t)(j * 32) * HD, bLdst + j * 4096);
#pragma unroll
    for (int j = 0; j < 4; ++j)
        gload16(agp + (size_t)(j * 32) * HD, aLdst + j * 4096);
    SBAR; asm volatile("s_waitcnt vmcnt(0)" ::: "memory"); SBAR;
    __builtin_amdgcn_s_barrier();
    SBAR;

    for (int t2 = 0; t2 < KT; t2 += 2) {
        tile_body<0>(t2,     agp, bgp, aLdst, bLdst,
                     pAk0, pAk1, pAk2, pAk3, pBk0, pBk1, pBk2, pBk3, acc);
        tile_body<1>(t2 + 1, agp, bgp, aLdst, bLdst,
                     pAk0, pAk1, pAk2, pAk3, pBk0, pBk1, pBk2, pBk3, acc);
    }

    // ---- epilogue (32x32 C/D layout: col = lane&31, row = (r&3)+8*(r>>2)+4*hi) ----
    const float bv0 = bias[c0 + wc * 64 + l31];
    const float bv1 = bias[c0 + wc * 64 + 32 + l31];
    const int col0 = c0 + wc * 64 + l31;

#pragma unroll
    for (int rf = 0; rf < 4; ++rf) {
#pragma unroll
        for (int r = 0; r < 16; ++r) {
            const int rowl = (r & 3) + 8 * (r >> 2) + 4 * hi;
            const int grow = row0 + wr * 128 + rf * 32 + rowl;
            const float v0 = acc[rf][0][r] + bv0;
            const float v1 = acc[rf][1][r] + bv1;
            float m = fmaxf(v0, v1);
#pragma unroll
            for (int msk = 1; msk < 32; msk <<= 1)
                m = fmaxf(m, __shfl_xor(m, msk));
            float s = __expf(v0 - m) + __expf(v1 - m);
#pragma unroll
            for (int msk = 1; msk < 32; msk <<= 1)
                s += __shfl_xor(s, msk);
            const int tg = target[grow];
            if (tg == col0)      tgtlog[model * BT + grow] = v0;
            if (tg == col0 + 32) tgtlog[model * BT + grow] = v1;
            if (l31 == 0) {
                const size_t po = ((size_t)(model * BT + grow) * NCHUNK + nb * 4 + wc) * 2;
                partials[po]     = m;
                partials[po + 1] = s;
            }
        }
    }
}

// ---------------- kernel 1 (fallback, f32 weights): R1 structure ----------------
__global__ __launch_bounds__(256) void gemm_lse_f32(
    const uint16_t* __restrict__ xbf,
    const float* __restrict__ w0, const float* __restrict__ b0,
    const float* __restrict__ w1, const float* __restrict__ b1,
    const int* __restrict__ target,
    float* __restrict__ partials, float* __restrict__ tgtlog)
{
    const int orig = blockIdx.x;               // grid 8000
    const int wgid = (orig & 7) * 1000 + (orig >> 3);
    const int mb    = wgid & 7;
    const int rest  = wgid >> 3;
    const int chunk = rest % 500;
    const int model = rest / 500;

    const float* w    = model ? w1 : w0;
    const float* bias = model ? b1 : b0;
    const uint16_t* xb = xbf + (size_t)model * BT * HD;

    const int row0 = mb * 256;
    const int c0   = chunk * 64;

    const int tid  = threadIdx.x;
    const int lane = tid & 63;
    const int wid  = tid >> 6;

    __shared__ uint16_t As_[256 * 64];
    __shared__ uint16_t Bs_[64 * 64];

    f32x4 acc[4][4];
#pragma unroll
    for (int i = 0; i < 4; ++i)
#pragma unroll
        for (int j = 0; j < 4; ++j) acc[i][j] = (f32x4){0.f, 0.f, 0.f, 0.f};

    const int srow8 = lane >> 3;
    const int slot  = (lane & 7) ^ srow8;
    const uint16_t* agsrc = xb + (size_t)(row0 + wid * 64 + srow8) * HD + slot * 8;
    char* aldst = (char*)As_ + wid * 8192;

    const int ss   = tid & 7;
    const int srow = tid >> 3;
    const int swz_w = (srow & 7) << 4;
    const float* bptr = w + (size_t)(c0 + srow) * HD + ss * 8;

    const int lane15 = lane & 15;
    const int kg     = lane >> 4;
    const int swz_r  = (lane & 7) << 4;

    for (int kt = 0; kt < 64; ++kt) {
        const int kofs = kt * 64;
#pragma unroll
        for (int c = 0; c < 8; ++c)
            gload16(agsrc + (size_t)c * 8 * HD + kofs, aldst + c * 1024);
        {
            float4 bv[2][2];
#pragma unroll
            for (int r = 0; r < 2; ++r) {
                const float* p = bptr + (size_t)r * 32 * HD + kofs;
                bv[r][0] = *(const float4*)(p);
                bv[r][1] = *(const float4*)(p + 4);
            }
#pragma unroll
            for (int r = 0; r < 2; ++r) {
                const int row_l = srow + r * 32;
                float fv[8] = {bv[r][0].x, bv[r][0].y, bv[r][0].z, bv[r][0].w,
                               bv[r][1].x, bv[r][1].y, bv[r][1].z, bv[r][1].w};
                uint32_t pk[4];
#pragma unroll
                for (int e = 0; e < 4; ++e)
                    pk[e] = (uint32_t)f2bf(fv[2 * e]) | ((uint32_t)f2bf(fv[2 * e + 1]) << 16);
                const int off = (row_l * 128 + ss * 16) ^ swz_w;
                *(uint4*)((char*)Bs_ + off) = *(uint4*)pk;
            }
        }
        __syncthreads();
#pragma unroll
        for (int ks = 0; ks < 2; ++ks) {
            short8 af[4], bf[4];
#pragma unroll
            for (int mi = 0; mi < 4; ++mi) {
                const int arow = wid * 64 + mi * 16 + lane15;
                const int off = (arow * 128 + ks * 64 + kg * 16) ^ swz_r;
                af[mi] = *(const short8*)((const char*)As_ + off);
            }
#pragma unroll
            for (int ni = 0; ni < 4; ++ni) {
                const int brow = ni * 16 + lane15;
                const int off = (brow * 128 + ks * 64 + kg * 16) ^ swz_r;
                bf[ni] = *(const short8*)((const char*)Bs_ + off);
            }
#pragma unroll
            for (int mi = 0; mi < 4; ++mi)
#pragma unroll
                for (int ni = 0; ni < 4; ++ni)
                    acc[mi][ni] = __builtin_amdgcn_mfma_f32_16x16x32_bf16(
                        af[mi], bf[ni], acc[mi][ni], 0, 0, 0);
        }
        __syncthreads();
    }

    float bv4[4];
#pragma unroll
    for (int ni = 0; ni < 4; ++ni) bv4[ni] = bias[c0 + ni * 16 + lane15];

#pragma unroll
    for (int mi = 0; mi < 4; ++mi) {
        const int grow_base = row0 + wid * 64 + mi * 16 + kg * 4;
#pragma unroll
        for (int j = 0; j < 4; ++j) {
            const int grow = grow_base + j;
            float v[4];
#pragma unroll
            for (int ni = 0; ni < 4; ++ni) v[ni] = acc[mi][ni][j] + bv4[ni];
            float m = fmaxf(fmaxf(v[0], v[1]), fmaxf(v[2], v[3]));
#pragma unroll
            for (int msk = 1; msk < 16; msk <<= 1)
                m = fmaxf(m, __shfl_xor(m, msk));
            float s = __expf(v[0] - m) + __expf(v[1] - m) +
                      __expf(v[2] - m) + __expf(v[3] - m);
#pragma unroll
            for (int msk = 1; msk < 16; msk <<= 1)
                s += __shfl_xor(s, msk);
            const int tg = target[grow];
#pragma unroll
            for (int ni = 0; ni < 4; ++ni) {
                const int gcol = c0 + ni * 16 + lane15;
                if (tg == gcol) tgtlog[model * BT + grow] = v[ni];
            }
            if (lane15 == 0) {
                const size_t po = ((size_t)(model * BT + grow) * NCHUNK + chunk) * 2;
                partials[po]     = m;
                partials[po + 1] = s;
            }
        }
    }
}

// ---------------- kernel 2: combine chunk partials -> lse -> per-token logp ----------------
__global__ void lse_reduce(const float* __restrict__ partials,
                           const float* __restrict__ tgtlog,
                           float* __restrict__ logp) {
    const int gw = blockIdx.x * (blockDim.x >> 6) + (threadIdx.x >> 6);
    if (gw >= 2 * BT) return;
    const int lane = threadIdx.x & 63;
    const float* p = partials + (size_t)gw * NCHUNK * 2;

    float m = -1e30f;
#pragma unroll
    for (int i = 0; i < 8; ++i) {
        const int c = lane + i * 64;
        if (c < NCHUNK) m = fmaxf(m, p[c * 2]);
    }
#pragma unroll
    for (int msk = 1; msk < 64; msk <<= 1) m = fmaxf(m, __shfl_xor(m, msk));
    float s = 0.f;
#pragma unroll
    for (int i = 0; i < 8; ++i) {
        const int c = lane + i * 64;
        if (c < NCHUNK) s += p[c * 2 + 1] * __expf(p[c * 2] - m);
    }
#pragma unroll
    for (int msk = 1; msk < 64; msk <<= 1) s += __shfl_xor(s, msk);
    if (lane == 0) {
        const float lse = m + __logf(s);
        logp[gw] = tgtlog[gw] - lse;
    }
}

// ---------------- kernel 3: KTO loss ----------------
__global__ void final_loss(const float* __restrict__ logp, const int* __restrict__ target,
                           const int* __restrict__ pref, const float* __restrict__ kl,
                           float* __restrict__ out) {
    const int t = threadIdx.x;          // 512 threads
    const int lane = t & 63, wv = t >> 6;
    __shared__ float rp[4][8], rr[4][8], rm[4][8];
#pragma unroll
    for (int b = 0; b < 4; ++b) {
        const int idx = b * TT + t;
        const int tg = target[idx];
        const bool mk = (tg != IGNORE_IDX);
        float lp = mk ? logp[idx] : 0.f;
        float lr = mk ? logp[BT + idx] : 0.f;
        float mc = mk ? 1.f : 0.f;
        for (int off = 32; off; off >>= 1) {
            lp += __shfl_down(lp, off);
            lr += __shfl_down(lr, off);
            mc += __shfl_down(mc, off);
        }
        if (lane == 0) { rp[b][wv] = lp; rr[b][wv] = lr; rm[b][wv] = mc; }
    }
    __syncthreads();
    if (t == 0) {
        float loss = 0.f;
        for (int b = 0; b < 4; ++b) {
            float sp = 0.f, sr = 0.f, sm = 0.f;
            for (int i = 0; i < 8; ++i) { sp += rp[b][i]; sr += rr[b][i]; sm += rm[b][i]; }
            const float denom = fmaxf(sm, 1.f);
            const float lrb = (sp - sr) / denom;
            const float mult = pref[b] ? 1.f : -1.f;
            const float z = 0.1f * (lrb - kl[0]) * mult;
            loss += 1.f / (1.f + __expf(z));   // 1 - sigmoid(z)
        }
        out[0] = loss * 0.25f;
    }
}

extern "C" void kernel_launch(void* const* d_in, const int* in_sizes, int n_in,
                              void* d_out, int out_size, void* d_ws, size_t ws_size,
                              hipStream_t stream) {
    const float* x    = (const float*)d_in[0];
    const float* w0   = (const float*)d_in[1];
    const float* b0   = (const float*)d_in[2];
    const int*   tgt  = (const int*)d_in[3];
    const int*   pref = (const int*)d_in[4];
    const float* xr   = (const float*)d_in[5];
    const float* w1   = (const float*)d_in[6];
    const float* b1   = (const float*)d_in[7];
    const float* kl   = (const float*)d_in[8];
    float* out = (float*)d_out;

    // ws layout: xbf | partials | tgtlog | logp | [wbf if it fits]
    const size_t xbf_b  = (size_t)2 * BT * HD * 2;          // 33.55 MB
    const size_t part_b = (size_t)2 * BT * NCHUNK * 2 * 4;  // 16.38 MB
    const size_t tl_b   = (size_t)2 * BT * 4;
    const size_t wbf_b  = (size_t)2 * VD * HD * 2;          // 524.3 MB

    char* wp = (char*)d_ws;
    uint16_t* xbf     = (uint16_t*)wp;                 wp += xbf_b;
    float*    partials = (float*)wp;                   wp += part_b;
    float*    tgtlog   = (float*)wp;                   wp += tl_b;
    float*    logp     = (float*)wp;                   wp += tl_b;
    uint16_t* wbf      = (uint16_t*)wp;
    const bool use_wbf = ws_size >= (xbf_b + part_b + 2 * tl_b + wbf_b);

    hipLaunchKernelGGL(convert_x, dim3(1024), dim3(256), 0, stream, x, xr, xbf);
    if (use_wbf) {
        hipLaunchKernelGGL(convert_w, dim3(4096), dim3(256), 0, stream, w0, w1, wbf);
        hipLaunchKernelGGL(gemm_lse_bf, dim3(NWG2), dim3(512), 0, stream,
                           xbf, wbf, b0, b1, tgt, partials, tgtlog);
    } else {
        hipLaunchKernelGGL(gemm_lse_f32, dim3(8000), dim3(256), 0, stream,
                           xbf, w0, b0, w1, b1, tgt, partials, tgtlog);
    }
    hipLaunchKernelGGL(lse_reduce, dim3(2 * BT / 4), dim3(256), 0, stream,
                       partials, tgtlog, logp);
    hipLaunchKernelGGL(final_loss, dim3(1), dim3(512), 0, stream, logp, tgt, pref, kl, out);
}

// Round 8
// 1505.035 us; speedup vs baseline: 1.0526x; 1.0526x over previous
//
#include <hip/hip_runtime.h>
#include <hip/hip_bf16.h>
#include <stdint.h>

#define HD 4096
#define VD 32000
#define BT 2048        // B*T rows
#define TT 512
#define IGNORE_IDX (-100)

// bf16 8-wave main GEMM geometry
#define BM 256
#define BN 256
#define BKT 64
#define KT (HD / BKT)          // 64 K-tiles
#define NB (VD / BN)           // 125
#define MB (BT / BM)           // 8
#define NWG2 (MB * NB * 2)     // 2000

// partials granularity (64 columns per chunk) — shared with f32 fallback
#define NCHUNK (VD / 64)       // 500

typedef __attribute__((ext_vector_type(8))) short short8;
typedef __attribute__((ext_vector_type(4))) float f32x4;

__device__ __forceinline__ uint16_t f2bf(float f) {
    uint32_t u = __float_as_uint(f);
    u += 0x7FFFu + ((u >> 16) & 1u);   // round-to-nearest-even
    return (uint16_t)(u >> 16);
}

__device__ __forceinline__ void gload16(const void* g, void* l) {
    __builtin_amdgcn_global_load_lds(
        (const __attribute__((address_space(1))) void*)g,
        (__attribute__((address_space(3))) void*)l, 16, 0, 0);
}

#define SBAR __builtin_amdgcn_sched_barrier(0)

// ---------------- kernel 0a: convert x inputs f32 -> bf16 ----------------
__global__ void convert_x(const float* __restrict__ x0, const float* __restrict__ x1,
                          uint16_t* __restrict__ xbf) {
    const int64_t n4 = (int64_t)BT * HD / 4;
    ushort4* o0 = (ushort4*)xbf;
    ushort4* o1 = (ushort4*)(xbf + (int64_t)BT * HD);
    for (int64_t i = blockIdx.x * (int64_t)blockDim.x + threadIdx.x; i < n4;
         i += (int64_t)gridDim.x * blockDim.x) {
        float4 a = ((const float4*)x0)[i];
        float4 b = ((const float4*)x1)[i];
        ushort4 ua, ub;
        ua.x = f2bf(a.x); ua.y = f2bf(a.y); ua.z = f2bf(a.z); ua.w = f2bf(a.w);
        ub.x = f2bf(b.x); ub.y = f2bf(b.y); ub.z = f2bf(b.z); ub.w = f2bf(b.w);
        o0[i] = ua;
        o1[i] = ub;
    }
}

// ---------------- kernel 0b: convert weights f32 -> bf16 ----------------
__global__ void convert_w(const float* __restrict__ w0, const float* __restrict__ w1,
                          uint16_t* __restrict__ wbf) {
    const int64_t n4 = (int64_t)VD * HD / 4;
    ushort4* o0 = (ushort4*)wbf;
    ushort4* o1 = (ushort4*)(wbf + (int64_t)VD * HD);
    for (int64_t i = blockIdx.x * (int64_t)blockDim.x + threadIdx.x; i < n4;
         i += (int64_t)gridDim.x * blockDim.x) {
        float4 a = ((const float4*)w0)[i];
        float4 b = ((const float4*)w1)[i];
        ushort4 ua, ub;
        ua.x = f2bf(a.x); ua.y = f2bf(a.y); ua.z = f2bf(a.z); ua.w = f2bf(a.w);
        ub.x = f2bf(b.x); ub.y = f2bf(b.y); ub.z = f2bf(b.z); ub.w = f2bf(b.w);
        o0[i] = ua;
        o1[i] = ub;
    }
}

// 16 MFMA cluster (one mi-pair quadrant x K=64), ks-major: 8 independent then 8.
__device__ __forceinline__ void mfma16(
    const short8& a0k0, const short8& a0k1, const short8& a1k0, const short8& a1k1,
    const short8 (&bfr)[4][2], f32x4* acc0, f32x4* acc1)
{
    __builtin_amdgcn_s_setprio(1);
#pragma unroll
    for (int ni = 0; ni < 4; ++ni)
        acc0[ni] = __builtin_amdgcn_mfma_f32_16x16x32_bf16(a0k0, bfr[ni][0], acc0[ni], 0, 0, 0);
#pragma unroll
    for (int ni = 0; ni < 4; ++ni)
        acc1[ni] = __builtin_amdgcn_mfma_f32_16x16x32_bf16(a1k0, bfr[ni][0], acc1[ni], 0, 0, 0);
#pragma unroll
    for (int ni = 0; ni < 4; ++ni)
        acc0[ni] = __builtin_amdgcn_mfma_f32_16x16x32_bf16(a0k1, bfr[ni][1], acc0[ni], 0, 0, 0);
#pragma unroll
    for (int ni = 0; ni < 4; ++ni)
        acc1[ni] = __builtin_amdgcn_mfma_f32_16x16x32_bf16(a1k1, bfr[ni][1], acc1[ni], 0, 0, 0);
    __builtin_amdgcn_s_setprio(0);
}

// ---------------- main GEMM tile body: 1 barrier per tile, free wave drift ----------------
// Tile t: issue ALL 8 prefetch gloads->NXT right after the tile-start barrier;
// then compute on CUR with NO intra-tile barriers (waves drift so ds_read and
// MFMA pipes overlap across waves); per-wave vmcnt(0) (loads issued a whole
// tile of compute earlier -> cheap) + s_barrier = tile-end join.
template<int CUR>
__device__ __forceinline__ void tile_body(
    int t,
    const uint16_t* __restrict__ agp, const uint16_t* __restrict__ bgp,
    char* aLdst, char* bLdst,
    const char* pA0, const char* pA1, const char* pB0, const char* pB1,
    f32x4 (&acc)[8][4])
{
    constexpr int CB  = CUR * 32768;
    constexpr int NXB = (CUR ^ 1) * 32768;
    const bool more = (t + 1) < KT;
    const int ko = (t + 1) * BKT;

    // ---- issue all 8 prefetch loads for tile t+1 (NXT free since tile start) ----
    if (more) {
#pragma unroll
        for (int j = 0; j < 4; ++j)
            gload16(bgp + (size_t)(j * 32) * HD + ko, bLdst + NXB + j * 4096);
#pragma unroll
        for (int j = 0; j < 4; ++j)
            gload16(agp + (size_t)(j * 32) * HD + ko, aLdst + NXB + j * 4096);
    }
    SBAR;

    // ---- compute on CUR (compiler-scheduled reads + MFMA, no barriers) ----
    short8 bfr[4][2];
#pragma unroll
    for (int ni = 0; ni < 4; ++ni) {
        bfr[ni][0] = *(const short8*)(pB0 + ni * 2048 + CB);
        bfr[ni][1] = *(const short8*)(pB1 + ni * 2048 + CB);
    }
#pragma unroll
    for (int p = 0; p < 4; ++p) {
        const short8 a0 = *(const short8*)(pA0 + (2 * p) * 2048 + CB);
        const short8 a1 = *(const short8*)(pA1 + (2 * p) * 2048 + CB);
        const short8 a2 = *(const short8*)(pA0 + (2 * p + 1) * 2048 + CB);
        const short8 a3 = *(const short8*)(pA1 + (2 * p + 1) * 2048 + CB);
        mfma16(a0, a1, a2, a3, bfr, acc[2 * p], acc[2 * p + 1]);
    }

    // ---- tile-end join ----
    SBAR;
    asm volatile("s_waitcnt vmcnt(0)" ::: "memory");
    SBAR;
    __builtin_amdgcn_s_barrier();
    SBAR;
}

// ---------------- kernel 1 (main): 256x256 GEMM + LSE partials ----------------
__global__ __launch_bounds__(512, 2) void gemm_lse_bf(
    const uint16_t* __restrict__ xbf, const uint16_t* __restrict__ wbf,
    const float* __restrict__ b0, const float* __restrict__ b1,
    const int* __restrict__ target,
    float* __restrict__ partials, float* __restrict__ tgtlog)
{
    __shared__ uint16_t As[2 * BM * BKT];  // 64 KB (2 buffers)
    __shared__ uint16_t Bs[2 * BN * BKT];  // 64 KB

    const int orig = blockIdx.x;
    const int wgid = (orig & 7) * (NWG2 / 8) + (orig >> 3);
    const int mb    = wgid & 7;
    const int rest  = wgid >> 3;
    const int nb    = rest % NB;
    const int model = rest / NB;

    const uint16_t* xb = xbf + (size_t)model * BT * HD;
    const uint16_t* wb = wbf + (size_t)model * VD * HD;
    const float* bias  = model ? b1 : b0;

    const int row0 = mb * BM;
    const int c0   = nb * BN;

    const int tid    = threadIdx.x;
    const int lane   = tid & 63;
    const int wid    = tid >> 6;       // 0..7
    const int wr     = wid >> 2;       // 0..1  (M half)
    const int wc     = wid & 3;        // 0..3  (N quarter)

    const int lane15 = lane & 15;
    const int kg     = lane >> 4;
    const int swz    = (lane & 7) << 4;

    // wave-local staging (verified R4/R5): wave stages ONLY its A-half and B-half
    // quadrant; LDS dest linear 1KB chunks, global source slot pre-swizzled.
    const int srow8 = lane >> 3;               // 0..7
    const int slot  = (lane & 7) ^ srow8;      // pre-swizzled source slot
    const uint16_t* agp = xb + (size_t)(row0 + wr * 128 + wc * 8 + srow8) * HD + slot * 8;
    const int bq = wr * 2 + (wc & 1);          // 0..3: stager index within B-half
    const uint16_t* bgp = wb + (size_t)(c0 + (wc >> 1) * 128 + bq * 8 + srow8) * HD + slot * 8;
    char* aLdst = (char*)As + wr * 16384 + wc * 1024;          // + j*4096 + buf*32768
    char* bLdst = (char*)Bs + (wc >> 1) * 16384 + bq * 1024;   // + j*4096 + buf*32768

    // fragment read base pointers (ks=0/1); +mi*2048 / +ni*2048, +buf*32768.
    // Proven 0-conflict 16x16 pattern (R5).
    const int arow_b = wr * 128 + lane15;
    const int brow_b = wc * 64 + lane15;
    const char* pA0 = (const char*)As + ((arow_b * 128 + 0  + kg * 16) ^ swz);
    const char* pA1 = (const char*)As + ((arow_b * 128 + 64 + kg * 16) ^ swz);
    const char* pB0 = (const char*)Bs + ((brow_b * 128 + 0  + kg * 16) ^ swz);
    const char* pB1 = (const char*)Bs + ((brow_b * 128 + 64 + kg * 16) ^ swz);

    f32x4 acc[8][4];
#pragma unroll
    for (int i = 0; i < 8; ++i)
#pragma unroll
        for (int j = 0; j < 4; ++j) acc[i][j] = (f32x4){0.f, 0.f, 0.f, 0.f};

    // prologue: stage tile 0 into buf 0, drain, barrier
#pragma unroll
    for (int j = 0; j < 4; ++j)
        gload16(bgp + (size_t)(j * 32) * HD, bLdst + j * 4096);
#pragma unroll
    for (int j = 0; j < 4; ++j)
        gload16(agp + (size_t)(j * 32) * HD, aLdst + j * 4096);
    SBAR; asm volatile("s_waitcnt vmcnt(0)" ::: "memory"); SBAR;
    __builtin_amdgcn_s_barrier();
    SBAR;

    for (int t2 = 0; t2 < KT; t2 += 2) {
        tile_body<0>(t2,     agp, bgp, aLdst, bLdst, pA0, pA1, pB0, pB1, acc);
        tile_body<1>(t2 + 1, agp, bgp, aLdst, bLdst, pA0, pA1, pB0, pB1, acc);
    }

    // ---- epilogue: bias, per-row max/sumexp over this wave's 64 cols ----
    float bv4[4];
#pragma unroll
    for (int ni = 0; ni < 4; ++ni) bv4[ni] = bias[c0 + wc * 64 + ni * 16 + lane15];

#pragma unroll
    for (int mi = 0; mi < 8; ++mi) {
        const int grow_base = row0 + wr * 128 + mi * 16 + kg * 4;
#pragma unroll
        for (int j = 0; j < 4; ++j) {
            const int grow = grow_base + j;
            float v[4];
#pragma unroll
            for (int ni = 0; ni < 4; ++ni) v[ni] = acc[mi][ni][j] + bv4[ni];
            float m = fmaxf(fmaxf(v[0], v[1]), fmaxf(v[2], v[3]));
#pragma unroll
            for (int msk = 1; msk < 16; msk <<= 1)
                m = fmaxf(m, __shfl_xor(m, msk));
            float s = __expf(v[0] - m) + __expf(v[1] - m) +
                      __expf(v[2] - m) + __expf(v[3] - m);
#pragma unroll
            for (int msk = 1; msk < 16; msk <<= 1)
                s += __shfl_xor(s, msk);
            const int tg = target[grow];
#pragma unroll
            for (int ni = 0; ni < 4; ++ni) {
                const int gcol = c0 + wc * 64 + ni * 16 + lane15;
                if (tg == gcol) tgtlog[model * BT + grow] = v[ni];
            }
            if (lane15 == 0) {
                const size_t po = ((size_t)(model * BT + grow) * NCHUNK + nb * 4 + wc) * 2;
                partials[po]     = m;
                partials[po + 1] = s;
            }
        }
    }
}

// ---------------- kernel 1 (fallback, f32 weights): R1 structure ----------------
__global__ __launch_bounds__(256) void gemm_lse_f32(
    const uint16_t* __restrict__ xbf,
    const float* __restrict__ w0, const float* __restrict__ b0,
    const float* __restrict__ w1, const float* __restrict__ b1,
    const int* __restrict__ target,
    float* __restrict__ partials, float* __restrict__ tgtlog)
{
    const int orig = blockIdx.x;               // grid 8000
    const int wgid = (orig & 7) * 1000 + (orig >> 3);
    const int mb    = wgid & 7;
    const int rest  = wgid >> 3;
    const int chunk = rest % 500;
    const int model = rest / 500;

    const float* w    = model ? w1 : w0;
    const float* bias = model ? b1 : b0;
    const uint16_t* xb = xbf + (size_t)model * BT * HD;

    const int row0 = mb * 256;
    const int c0   = chunk * 64;

    const int tid  = threadIdx.x;
    const int lane = tid & 63;
    const int wid  = tid >> 6;

    __shared__ uint16_t As_[256 * 64];
    __shared__ uint16_t Bs_[64 * 64];

    f32x4 acc[4][4];
#pragma unroll
    for (int i = 0; i < 4; ++i)
#pragma unroll
        for (int j = 0; j < 4; ++j) acc[i][j] = (f32x4){0.f, 0.f, 0.f, 0.f};

    const int srow8 = lane >> 3;
    const int slot  = (lane & 7) ^ srow8;
    const uint16_t* agsrc = xb + (size_t)(row0 + wid * 64 + srow8) * HD + slot * 8;
    char* aldst = (char*)As_ + wid * 8192;

    const int ss   = tid & 7;
    const int srow = tid >> 3;
    const int swz_w = (srow & 7) << 4;
    const float* bptr = w + (size_t)(c0 + srow) * HD + ss * 8;

    const int lane15 = lane & 15;
    const int kg     = lane >> 4;
    const int swz_r  = (lane & 7) << 4;

    for (int kt = 0; kt < 64; ++kt) {
        const int kofs = kt * 64;
#pragma unroll
        for (int c = 0; c < 8; ++c)
            gload16(agsrc + (size_t)c * 8 * HD + kofs, aldst + c * 1024);
        {
            float4 bv[2][2];
#pragma unroll
            for (int r = 0; r < 2; ++r) {
                const float* p = bptr + (size_t)r * 32 * HD + kofs;
                bv[r][0] = *(const float4*)(p);
                bv[r][1] = *(const float4*)(p + 4);
            }
#pragma unroll
            for (int r = 0; r < 2; ++r) {
                const int row_l = srow + r * 32;
                float fv[8] = {bv[r][0].x, bv[r][0].y, bv[r][0].z, bv[r][0].w,
                               bv[r][1].x, bv[r][1].y, bv[r][1].z, bv[r][1].w};
                uint32_t pk[4];
#pragma unroll
                for (int e = 0; e < 4; ++e)
                    pk[e] = (uint32_t)f2bf(fv[2 * e]) | ((uint32_t)f2bf(fv[2 * e + 1]) << 16);
                const int off = (row_l * 128 + ss * 16) ^ swz_w;
                *(uint4*)((char*)Bs_ + off) = *(uint4*)pk;
            }
        }
        __syncthreads();
#pragma unroll
        for (int ks = 0; ks < 2; ++ks) {
            short8 af[4], bf[4];
#pragma unroll
            for (int mi = 0; mi < 4; ++mi) {
                const int arow = wid * 64 + mi * 16 + lane15;
                const int off = (arow * 128 + ks * 64 + kg * 16) ^ swz_r;
                af[mi] = *(const short8*)((const char*)As_ + off);
            }
#pragma unroll
            for (int ni = 0; ni < 4; ++ni) {
                const int brow = ni * 16 + lane15;
                const int off = (brow * 128 + ks * 64 + kg * 16) ^ swz_r;
                bf[ni] = *(const short8*)((const char*)Bs_ + off);
            }
#pragma unroll
            for (int mi = 0; mi < 4; ++mi)
#pragma unroll
                for (int ni = 0; ni < 4; ++ni)
                    acc[mi][ni] = __builtin_amdgcn_mfma_f32_16x16x32_bf16(
                        af[mi], bf[ni], acc[mi][ni], 0, 0, 0);
        }
        __syncthreads();
    }

    float bv4[4];
#pragma unroll
    for (int ni = 0; ni < 4; ++ni) bv4[ni] = bias[c0 + ni * 16 + lane15];

#pragma unroll
    for (int mi = 0; mi < 4; ++mi) {
        const int grow_base = row0 + wid * 64 + mi * 16 + kg * 4;
#pragma unroll
        for (int j = 0; j < 4; ++j) {
            const int grow = grow_base + j;
            float v[4];
#pragma unroll
            for (int ni = 0; ni < 4; ++ni) v[ni] = acc[mi][ni][j] + bv4[ni];
            float m = fmaxf(fmaxf(v[0], v[1]), fmaxf(v[2], v[3]));
#pragma unroll
            for (int msk = 1; msk < 16; msk <<= 1)
                m = fmaxf(m, __shfl_xor(m, msk));
            float s = __expf(v[0] - m) + __expf(v[1] - m) +
                      __expf(v[2] - m) + __expf(v[3] - m);
#pragma unroll
            for (int msk = 1; msk < 16; msk <<= 1)
                s += __shfl_xor(s, msk);
            const int tg = target[grow];
#pragma unroll
            for (int ni = 0; ni < 4; ++ni) {
                const int gcol = c0 + ni * 16 + lane15;
                if (tg == gcol) tgtlog[model * BT + grow] = v[ni];
            }
            if (lane15 == 0) {
                const size_t po = ((size_t)(model * BT + grow) * NCHUNK + chunk) * 2;
                partials[po]     = m;
                partials[po + 1] = s;
            }
        }
    }
}

// ---------------- kernel 2: combine chunk partials -> lse -> per-token logp ----------------
__global__ void lse_reduce(const float* __restrict__ partials,
                           const float* __restrict__ tgtlog,
                           float* __restrict__ logp) {
    const int gw = blockIdx.x * (blockDim.x >> 6) + (threadIdx.x >> 6);
    if (gw >= 2 * BT) return;
    const int lane = threadIdx.x & 63;
    const float* p = partials + (size_t)gw * NCHUNK * 2;

    float m = -1e30f;
#pragma unroll
    for (int i = 0; i < 8; ++i) {
        const int c = lane + i * 64;
        if (c < NCHUNK) m = fmaxf(m, p[c * 2]);
    }
#pragma unroll
    for (int msk = 1; msk < 64; msk <<= 1) m = fmaxf(m, __shfl_xor(m, msk));
    float s = 0.f;
#pragma unroll
    for (int i = 0; i < 8; ++i) {
        const int c = lane + i * 64;
        if (c < NCHUNK) s += p[c * 2 + 1] * __expf(p[c * 2] - m);
    }
#pragma unroll
    for (int msk = 1; msk < 64; msk <<= 1) s += __shfl_xor(s, msk);
    if (lane == 0) {
        const float lse = m + __logf(s);
        logp[gw] = tgtlog[gw] - lse;
    }
}

// ---------------- kernel 3: KTO loss ----------------
__global__ void final_loss(const float* __restrict__ logp, const int* __restrict__ target,
                           const int* __restrict__ pref, const float* __restrict__ kl,
                           float* __restrict__ out) {
    const int t = threadIdx.x;          // 512 threads
    const int lane = t & 63, wv = t >> 6;
    __shared__ float rp[4][8], rr[4][8], rm[4][8];
#pragma unroll
    for (int b = 0; b < 4; ++b) {
        const int idx = b * TT + t;
        const int tg = target[idx];
        const bool mk = (tg != IGNORE_IDX);
        float lp = mk ? logp[idx] : 0.f;
        float lr = mk ? logp[BT + idx] : 0.f;
        float mc = mk ? 1.f : 0.f;
        for (int off = 32; off; off >>= 1) {
            lp += __shfl_down(lp, off);
            lr += __shfl_down(lr, off);
            mc += __shfl_down(mc, off);
        }
        if (lane == 0) { rp[b][wv] = lp; rr[b][wv] = lr; rm[b][wv] = mc; }
    }
    __syncthreads();
    if (t == 0) {
        float loss = 0.f;
        for (int b = 0; b < 4; ++b) {
            float sp = 0.f, sr = 0.f, sm = 0.f;
            for (int i = 0; i < 8; ++i) { sp += rp[b][i]; sr += rr[b][i]; sm += rm[b][i]; }
            const float denom = fmaxf(sm, 1.f);
            const float lrb = (sp - sr) / denom;
            const float mult = pref[b] ? 1.f : -1.f;
            const float z = 0.1f * (lrb - kl[0]) * mult;
            loss += 1.f / (1.f + __expf(z));   // 1 - sigmoid(z)
        }
        out[0] = loss * 0.25f;
    }
}

extern "C" void kernel_launch(void* const* d_in, const int* in_sizes, int n_in,
                              void* d_out, int out_size, void* d_ws, size_t ws_size,
                              hipStream_t stream) {
    const float* x    = (const float*)d_in[0];
    const float* w0   = (const float*)d_in[1];
    const float* b0   = (const float*)d_in[2];
    const int*   tgt  = (const int*)d_in[3];
    const int*   pref = (const int*)d_in[4];
    const float* xr   = (const float*)d_in[5];
    const float* w1   = (const float*)d_in[6];
    const float* b1   = (const float*)d_in[7];
    const float* kl   = (const float*)d_in[8];
    float* out = (float*)d_out;

    // ws layout: xbf | partials | tgtlog | logp | [wbf if it fits]
    const size_t xbf_b  = (size_t)2 * BT * HD * 2;          // 33.55 MB
    const size_t part_b = (size_t)2 * BT * NCHUNK * 2 * 4;  // 16.38 MB
    const size_t tl_b   = (size_t)2 * BT * 4;
    const size_t wbf_b  = (size_t)2 * VD * HD * 2;          // 524.3 MB

    char* wp = (char*)d_ws;
    uint16_t* xbf     = (uint16_t*)wp;                 wp += xbf_b;
    float*    partials = (float*)wp;                   wp += part_b;
    float*    tgtlog   = (float*)wp;                   wp += tl_b;
    float*    logp     = (float*)wp;                   wp += tl_b;
    uint16_t* wbf      = (uint16_t*)wp;
    const bool use_wbf = ws_size >= (xbf_b + part_b + 2 * tl_b + wbf_b);

    hipLaunchKernelGGL(convert_x, dim3(1024), dim3(256), 0, stream, x, xr, xbf);
    if (use_wbf) {
        hipLaunchKernelGGL(convert_w, dim3(4096), dim3(256), 0, stream, w0, w1, wbf);
        hipLaunchKernelGGL(gemm_lse_bf, dim3(NWG2), dim3(512), 0, stream,
                           xbf, wbf, b0, b1, tgt, partials, tgtlog);
    } else {
        hipLaunchKernelGGL(gemm_lse_f32, dim3(8000), dim3(256), 0, stream,
                           xbf, w0, b0, w1, b1, tgt, partials, tgtlog);
    }
    hipLaunchKernelGGL(lse_reduce, dim3(2 * BT / 4), dim3(256), 0, stream,
                       partials, tgtlog, logp);
    hipLaunchKernelGGL(final_loss, dim3(1), dim3(512), 0, stream, logp, tgt, pref, kl, out);
}